// Round 1
// baseline (120.724 us; speedup 1.0000x reference)
//
#include <hip/hip_runtime.h>

namespace {
constexpr int Bn = 8, Cn = 256, Hn = 96, Wn = 128;
constexpr int HWn = Hn * Wn;          // 12288
constexpr int CHWn = Cn * HWn;
constexpr int ND = 9;                 // 2*MD+1
constexpr int STRIDE = 140;           // LDS row stride in words; 140/4=35 ≡ 3 (mod 8) -> even bank spread
constexpr int TILESH = Hn / 4;        // 24 tiles of 4 h-rows
constexpr int NBLK = Bn * TILESH * ND; // 1728 one-wave blocks
constexpr int PERX = NBLK / 8;        // 216 blocks per XCD -> exactly one batch image per XCD
}

__global__ __launch_bounds__(64) void corr_kernel(
    const float* __restrict__ first, const float* __restrict__ second,
    float* __restrict__ out)
{
  __shared__ __align__(16) float sbuf[2][4 * STRIDE];

  const int lane = threadIdx.x;
  const int bid = blockIdx.x;
  // XCD-aware swizzle: blocks with bid%8==x (-> XCD x) map to logical range [216x, 216x+215],
  // i.e. XCD x processes batch image b=x entirely -> second rows reused within one L2.
  const int logical = (bid & 7) * PERX + (bid >> 3);
  const int dy = logical % ND;
  const int t = logical / ND;
  const int b = t / TILESH;
  const int h0 = (t % TILESH) * 4;

  // compute mapping: 16 lanes per h-row, 8 pixels per lane
  const int hs = lane >> 4;            // 0..3
  const int w0 = (lane & 15) << 3;     // 0..120

  // staging mapping: 4 rows x 32 16B-chunks = 128 chunks = 64 lanes x 2 slots
  const int r0 = lane >> 5;            // 0..1  (slot0 row; slot1 row = r0+2)
  const int cc = lane & 31;            // chunk col (global cols 4cc..4cc+3)

  const int gr0 = h0 + dy - 4 + r0;
  const int gr1 = gr0 + 2;
  const float m0 = (gr0 >= 0 && gr0 < Hn) ? 1.0f : 0.0f;
  const float m1 = (gr1 >= 0 && gr1 < Hn) ? 1.0f : 0.0f;
  const int cg0 = min(max(gr0, 0), Hn - 1);   // clamped (safe) source rows
  const int cg1 = min(max(gr1, 0), Hn - 1);

  const float* src0 = second + b * CHWn + cg0 * Wn + 4 * cc;
  const float* src1 = second + b * CHWn + cg1 * Wn + 4 * cc;
  const float* fsrc = first + b * CHWn + (h0 + hs) * Wn + w0;

  const int dw0 = STRIDE * r0 + 4 + 4 * cc;        // word offset, +4 = left halo pad
  const int dw1 = STRIDE * (r0 + 2) + 4 + 4 * cc;
  const int srw = STRIDE * hs + w0;                // read base: col w0-4 is word srw

  // zero the halo pad chunks (cols -4..-1 and 128..131) of both buffers, once
  if (lane < 16) {
    const int bsel = lane >> 3;
    const int row = (lane >> 1) & 3;
    const int side = lane & 1;
    *(float4*)&sbuf[bsel][STRIDE * row + (side ? 132 : 0)] =
        make_float4(0.f, 0.f, 0.f, 0.f);
  }

  float acc[ND][8];
#pragma unroll
  for (int dx = 0; dx < ND; ++dx)
#pragma unroll
    for (int p = 0; p < 8; ++p) acc[dx][p] = 0.f;

  // prologue: stage channel 0 into buffer 0
  float4 st0 = *(const float4*)src0;
  float4 st1 = *(const float4*)src1;
  float4 fa = *(const float4*)fsrc;
  float4 fb = *(const float4*)(fsrc + 4);
  src0 += HWn; src1 += HWn; fsrc += HWn;
  st0.x *= m0; st0.y *= m0; st0.z *= m0; st0.w *= m0;
  st1.x *= m1; st1.y *= m1; st1.z *= m1; st1.w *= m1;
  *(float4*)&sbuf[0][dw0] = st0;
  *(float4*)&sbuf[0][dw1] = st1;

#pragma unroll 2
  for (int c = 0; c < Cn; ++c) {
    const int cur = c & 1;
    float4 nst0, nst1, nfa, nfb;
    if (c < Cn - 1) {   // prefetch next channel (uniform branch)
      nst0 = *(const float4*)src0;
      nst1 = *(const float4*)src1;
      nfa = *(const float4*)fsrc;
      nfb = *(const float4*)(fsrc + 4);
      src0 += HWn; src1 += HWn; fsrc += HWn;
    } else {
      nst0 = nst1 = nfa = nfb = make_float4(0.f, 0.f, 0.f, 0.f);
    }

    // read 16-float second window (cols w0-4 .. w0+11) for this thread's row
    const float* sb = &sbuf[cur][srw];
    float4 q0 = *(const float4*)(sb + 0);
    float4 q1 = *(const float4*)(sb + 4);
    float4 q2 = *(const float4*)(sb + 8);
    float4 q3 = *(const float4*)(sb + 12);
    const float s[16] = {q0.x, q0.y, q0.z, q0.w, q1.x, q1.y, q1.z, q1.w,
                         q2.x, q2.y, q2.z, q2.w, q3.x, q3.y, q3.z, q3.w};
    const float f[8] = {fa.x, fa.y, fa.z, fa.w, fb.x, fb.y, fb.z, fb.w};

#pragma unroll
    for (int dx = 0; dx < ND; ++dx)
#pragma unroll
      for (int p = 0; p < 8; ++p)
        acc[dx][p] = fmaf(f[p], s[p + dx], acc[dx][p]);

    if (c < Cn - 1) {
      nst0.x *= m0; nst0.y *= m0; nst0.z *= m0; nst0.w *= m0;
      nst1.x *= m1; nst1.y *= m1; nst1.z *= m1; nst1.w *= m1;
      const int nxt = cur ^ 1;
      *(float4*)&sbuf[nxt][dw0] = nst0;
      *(float4*)&sbuf[nxt][dw1] = nst1;
    }
    fa = nfa; fb = nfb;
  }

  const float sc = 1.0f / Cn;
  float* obase = out + ((b * 81 + dy * ND) * Hn + (h0 + hs)) * Wn + w0;
#pragma unroll
  for (int dx = 0; dx < ND; ++dx) {
    float4 o0 = make_float4(acc[dx][0] * sc, acc[dx][1] * sc,
                            acc[dx][2] * sc, acc[dx][3] * sc);
    float4 o1 = make_float4(acc[dx][4] * sc, acc[dx][5] * sc,
                            acc[dx][6] * sc, acc[dx][7] * sc);
    *(float4*)(obase + dx * HWn) = o0;
    *(float4*)(obase + dx * HWn + 4) = o1;
  }
}

extern "C" void kernel_launch(void* const* d_in, const int* in_sizes, int n_in,
                              void* d_out, int out_size, void* d_ws, size_t ws_size,
                              hipStream_t stream) {
  const float* first = (const float*)d_in[0];
  const float* second = (const float*)d_in[1];
  float* out = (float*)d_out;
  corr_kernel<<<dim3(NBLK), dim3(64), 0, stream>>>(first, second, out);
}

// Round 2
// 98.270 us; speedup vs baseline: 1.2285x; 1.2285x over previous
//
#include <hip/hip_runtime.h>

namespace {
constexpr int Bn = 8, Cn = 256, Hn = 96, Wn = 128;
constexpr int HWn = Hn * Wn;            // 12288
constexpr int CHWn = Cn * HWn;
constexpr int ND = 9;                   // 2*MD+1
constexpr int TILESH = Hn / 4;          // 24 tiles of 4 h-rows
constexpr int NBLK = Bn * TILESH * ND;  // 1728 one-wave blocks
constexpr int PERX = NBLK / 8;          // 216 blocks/XCD -> one batch image per XCD
}

// DPP lane shifts within 16-lane rows; bound_ctrl=true -> shifted-in lanes read 0
// (this IS the w-direction zero padding at tile edges).
__device__ __forceinline__ float dpp_shr1(float x) {  // lane i <- lane i-1 (row-local)
  return __int_as_float(__builtin_amdgcn_update_dpp(
      0, __float_as_int(x), 0x111 /*row_shr:1*/, 0xF, 0xF, true));
}
__device__ __forceinline__ float dpp_shl1(float x) {  // lane i <- lane i+1 (row-local)
  return __int_as_float(__builtin_amdgcn_update_dpp(
      0, __float_as_int(x), 0x101 /*row_shl:1*/, 0xF, 0xF, true));
}

struct Ch {
  float4 sa, sb, fa, fb;
};

__global__ __launch_bounds__(64, 2) void corr_kernel(
    const float* __restrict__ first, const float* __restrict__ second,
    float* __restrict__ out)
{
  const int lane = threadIdx.x;
  const int bid = blockIdx.x;
  // XCD-aware swizzle: XCD x handles batch image b=x -> second re-reads stay in its L2.
  const int logical = (bid & 7) * PERX + (bid >> 3);
  const int dy = logical % ND;
  const int t = logical / ND;
  const int b = t / TILESH;
  const int h0 = (t % TILESH) * 4;

  const int hs = lane >> 4;          // 0..3: h-row within tile (= DPP row group)
  const int w0 = (lane & 15) << 3;   // 0..120: 8 pixels per lane

  const int gr = h0 + hs + dy - 4;                    // second source row
  const float m = (gr >= 0 && gr < Hn) ? 1.0f : 0.0f; // uniform within each 16-lane row
  const int cg = min(max(gr, 0), Hn - 1);             // clamped (safe) row

  const float* ssrc = second + b * CHWn + cg * Wn + w0;
  const float* fsrc = first + b * CHWn + (h0 + hs) * Wn + w0;

  float acc[ND][8];
#pragma unroll
  for (int dx = 0; dx < ND; ++dx)
#pragma unroll
    for (int p = 0; p < 8; ++p) acc[dx][p] = 0.f;

  auto LOADCH = [&](int coff) -> Ch {
    Ch r;
    r.sa = *(const float4*)(ssrc + coff);
    r.sb = *(const float4*)(ssrc + coff + 4);
    r.fa = *(const float4*)(fsrc + coff);
    r.fb = *(const float4*)(fsrc + coff + 4);
    return r;
  };

  auto COMP = [&](const Ch& ch) {
    // mask second row (OOB rows -> 0), BEFORE the lane shifts (m is row-uniform)
    const float sa0 = ch.sa.x * m, sa1 = ch.sa.y * m, sa2 = ch.sa.z * m, sa3 = ch.sa.w * m;
    const float sb0 = ch.sb.x * m, sb1 = ch.sb.y * m, sb2 = ch.sb.z * m, sb3 = ch.sb.w * m;
    // 16-float window cols w0-4 .. w0+11: halos from neighbor lanes via DPP
    const float s[16] = {
        dpp_shr1(sb0), dpp_shr1(sb1), dpp_shr1(sb2), dpp_shr1(sb3),
        sa0, sa1, sa2, sa3,
        sb0, sb1, sb2, sb3,
        dpp_shl1(sa0), dpp_shl1(sa1), dpp_shl1(sa2), dpp_shl1(sa3)};
    const float f[8] = {ch.fa.x, ch.fa.y, ch.fa.z, ch.fa.w,
                        ch.fb.x, ch.fb.y, ch.fb.z, ch.fb.w};
#pragma unroll
    for (int dx = 0; dx < ND; ++dx)
#pragma unroll
      for (int p = 0; p < 8; ++p)
        acc[dx][p] = fmaf(f[p], s[p + dx], acc[dx][p]);
  };

  // depth-2 register pipeline: loads for c+2/c+3 in flight while computing c/c+1
  Ch L0 = LOADCH(0);
  Ch L1 = LOADCH(HWn);
  int coff = 2 * HWn;
#pragma unroll 1
  for (int it = 0; it < (Cn - 2) / 2; ++it) {  // 127 iters, computes c=0..253
    Ch N0 = LOADCH(coff);
    Ch N1 = LOADCH(coff + HWn);
    COMP(L0);
    COMP(L1);
    L0 = N0;
    L1 = N1;
    coff += 2 * HWn;
  }
  COMP(L0);  // c = 254
  COMP(L1);  // c = 255

  const float sc = 1.0f / Cn;
  float* obase = out + ((b * 81 + dy * ND) * Hn + (h0 + hs)) * Wn + w0;
#pragma unroll
  for (int dx = 0; dx < ND; ++dx) {
    float4 o0 = make_float4(acc[dx][0] * sc, acc[dx][1] * sc,
                            acc[dx][2] * sc, acc[dx][3] * sc);
    float4 o1 = make_float4(acc[dx][4] * sc, acc[dx][5] * sc,
                            acc[dx][6] * sc, acc[dx][7] * sc);
    *(float4*)(obase + dx * HWn) = o0;
    *(float4*)(obase + dx * HWn + 4) = o1;
  }
}

extern "C" void kernel_launch(void* const* d_in, const int* in_sizes, int n_in,
                              void* d_out, int out_size, void* d_ws, size_t ws_size,
                              hipStream_t stream) {
  const float* first = (const float*)d_in[0];
  const float* second = (const float*)d_in[1];
  float* out = (float*)d_out;
  corr_kernel<<<dim3(NBLK), dim3(64), 0, stream>>>(first, second, out);
}